// Round 6
// baseline (181.665 us; speedup 1.0000x reference)
//
#include <hip/hip_runtime.h>
#include <math.h>

// Problem constants (N,C,H,W,D) = (64, 3, 256, 256, 512)
#define N_B 64
#define C_CH 3
#define H_IMG 256
#define W_IMG 256
#define D_FEAT 512

#define OUT_OFF_GRID   12582912
#define OUT_OFF_MATRIX 20971520
#define OUT_OFF_AFFINE 20971904

// native clang vectors (accepted by __builtin_nontemporal_store)
typedef float v4f __attribute__((ext_vector_type(4)));
typedef float v2f __attribute__((ext_vector_type(2)));

// ------------------------------------------------------------------
// Kernel 1: per-batch linear head -> affine matrix + level
// ------------------------------------------------------------------
__global__ void params_kernel(const float* __restrict__ features,
                              const float* __restrict__ lin_w,
                              const float* __restrict__ lin_b,
                              float* __restrict__ out_matrix,
                              float* __restrict__ out_affine,
                              float* __restrict__ ws_params)
{
    const int n = blockIdx.x;
    const int t = threadIdx.x;
    const float* f = features + n * D_FEAT;
    float f0 = f[t];
    float f1 = f[t + 256];
    float a0 = f0 * lin_w[0 * D_FEAT + t] + f1 * lin_w[0 * D_FEAT + t + 256];
    float a1 = f0 * lin_w[1 * D_FEAT + t] + f1 * lin_w[1 * D_FEAT + t + 256];
    float a2 = f0 * lin_w[2 * D_FEAT + t] + f1 * lin_w[2 * D_FEAT + t + 256];
    float a3 = f0 * lin_w[3 * D_FEAT + t] + f1 * lin_w[3 * D_FEAT + t + 256];

    __shared__ float red[4][256];
    red[0][t] = a0; red[1][t] = a1; red[2][t] = a2; red[3][t] = a3;
    __syncthreads();
    for (int s = 128; s > 0; s >>= 1) {
        if (t < s) {
            red[0][t] += red[0][t + s];
            red[1][t] += red[1][t + s];
            red[2][t] += red[2][t + s];
            red[3][t] += red[3][t + s];
        }
        __syncthreads();
    }
    if (t == 0) {
        float p0 = red[0][0] + lin_b[0];
        float p1 = red[1][0] + lin_b[1];
        float p2 = red[2][0] + lin_b[2];
        float p3 = red[3][0] + lin_b[3];
        float rot   = tanhf(p0) * 3.14159265358979323846f;
        float scale = expf(p1);
        float c = cosf(rot), s = sinf(rot);
        float m00 = scale * c, m01 = -scale * s, m02 = p2;
        float m10 = scale * s, m11 =  scale * c, m12 = p3;
        out_matrix[n * 6 + 0] = m00;
        out_matrix[n * 6 + 1] = m01;
        out_matrix[n * 6 + 2] = m02;
        out_matrix[n * 6 + 3] = m10;
        out_matrix[n * 6 + 4] = m11;
        out_matrix[n * 6 + 5] = m12;
        out_affine[n * 4 + 0] = rot;
        out_affine[n * 4 + 1] = scale;
        out_affine[n * 4 + 2] = p2;
        out_affine[n * 4 + 3] = p3;
        // affine grid => Jacobian norm is exactly `scale` in both directions
        float lv = log2f(fmaxf(scale, 1.0f));
        lv = fminf(fmaxf(lv, 0.0f), 2.5f);
        ws_params[n * 8 + 0] = m00;
        ws_params[n * 8 + 1] = m01;
        ws_params[n * 8 + 2] = m02;
        ws_params[n * 8 + 3] = m10;
        ws_params[n * 8 + 4] = m11;
        ws_params[n * 8 + 5] = m12;
        ws_params[n * 8 + 6] = lv;
        ws_params[n * 8 + 7] = 0.0f;
    }
}

// ------------------------------------------------------------------
// Kernel 2: depthwise 4x4 binomial blur, reflect (1,2), stride 2.
// Early-exits whole image planes whose pyramid level is never sampled
// (block-uniform: blocks never straddle an (n,c) plane).
// ------------------------------------------------------------------
template<int Hs, int Ws>
__global__ void down_kernel(const float* __restrict__ src, float* __restrict__ dst,
                            const float* __restrict__ ws_params, float lvl_gate)
{
    constexpr int Hd = Hs / 2, Wd = Ws / 2;
    constexpr int QUADS = Wd / 4;

    const int idx = blockIdx.x * blockDim.x + threadIdx.x;
    const int nc  = idx / (QUADS * Hd);          // pow2 divisor
    const int n   = nc / C_CH;

    // this level is sampled only if lv > lvl_gate for batch n
    if (ws_params[n * 8 + 6] <= lvl_gate) return;

    const int t   = idx & (QUADS - 1);
    const int i   = (idx / QUADS) & (Hd - 1);

    const float* __restrict__ s = src + (size_t)nc * Hs * Ws;

    int r[4];
#pragma unroll
    for (int a = 0; a < 4; a++) {
        int q = 2 * i + a - 1;
        if (q < 0) q = -q;
        if (q >= Hs) q = 2 * Hs - 2 - q;
        r[a] = q;
    }
    const int c8 = 8 * t;
    const int li = (t > 0)         ? c8 - 1 : 1;       // reflect -1 -> 1
    const int ri = (t < QUADS - 1) ? c8 + 8 : Ws - 2;  // reflect Ws -> Ws-2

    const float k0 = 0.125f, k1 = 0.375f;
    const float kr[4] = {0.125f, 0.375f, 0.375f, 0.125f};

    float acc0 = 0.f, acc1 = 0.f, acc2 = 0.f, acc3 = 0.f;
#pragma unroll
    for (int a = 0; a < 4; a++) {
        const float* row = s + (size_t)r[a] * Ws;
        float4 A = *(const float4*)(row + c8);
        float4 B = *(const float4*)(row + c8 + 4);
        float L = row[li];
        float R = row[ri];
        float h0 = k0 * L   + k1 * A.x + k1 * A.y + k0 * A.z;
        float h1 = k0 * A.y + k1 * A.z + k1 * A.w + k0 * B.x;
        float h2 = k0 * A.w + k1 * B.x + k1 * B.y + k0 * B.z;
        float h3 = k0 * B.y + k1 * B.z + k1 * B.w + k0 * R;
        acc0 += kr[a] * h0;
        acc1 += kr[a] * h1;
        acc2 += kr[a] * h2;
        acc3 += kr[a] * h3;
    }
    float4* d4 = (float4*)(dst + (size_t)nc * Hd * Wd + (size_t)i * Wd + 4 * t);
    *d4 = make_float4(acc0, acc1, acc2, acc3);
}

// ------------------------------------------------------------------
// Kernel 3: affine grid + mipmap bilinear warp.
// 2 x-adjacent pixels per thread; 64x8 tile per block.
// x-tap pairs fetched as one (unaligned-ok) float2.
// ------------------------------------------------------------------
__device__ __forceinline__ const float* lvl_ptr(int l, const float* img,
                                                const float* p1, const float* p2,
                                                const float* p3)
{
    return (l == 0) ? img : ((l == 1) ? p1 : ((l == 2) ? p2 : p3));
}

// bilinear sample of 3 channels at level l using paired x-loads
__device__ __forceinline__ void sample_level_pair(const float* __restrict__ base, int l,
                                                  float X, float Y, float out[3])
{
    const int Wl = W_IMG >> l;
    const int Hl = H_IMG >> l;
    float x = (X + 1.0f) * (0.5f * (float)Wl) - 0.5f;
    float y = (Y + 1.0f) * (0.5f * (float)Hl) - 0.5f;
    float x0f = floorf(x), y0f = floorf(y);
    float tx = x - x0f, ty = y - y0f;
    int x0 = (int)x0f, y0 = (int)y0f;
    int y0i = min(max(y0,     0), Hl - 1);
    int y1i = min(max(y0 + 1, 0), Hl - 1);
    int xp = min(max(x0, 0), Wl - 2);     // pair base col: [xp, xp+1] in range
    const bool selHi0 = (x0 >= Wl - 1);   // tap0 takes .y (right border clamp)
    const bool selLo1 = (x0 < 0);         // tap1 takes .x (left border clamp)
    float w00 = (1.0f - tx) * (1.0f - ty);
    float w01 = tx * (1.0f - ty);
    float w10 = (1.0f - tx) * ty;
    float w11 = tx * ty;
#pragma unroll
    for (int c = 0; c < C_CH; c++) {
        const float* pc = base + (size_t)c * Hl * Wl;
        float2 a = *(const float2*)(pc + y0i * Wl + xp);
        float2 b = *(const float2*)(pc + y1i * Wl + xp);
        float t00 = selHi0 ? a.y : a.x;
        float t01 = selLo1 ? a.x : a.y;
        float t10 = selHi0 ? b.y : b.x;
        float t11 = selLo1 ? b.x : b.y;
        out[c] = w00 * t00 + w01 * t01 + w10 * t10 + w11 * t11;
    }
}

__global__ void warp_kernel(const float* __restrict__ img,
                            const float* __restrict__ pyr1,
                            const float* __restrict__ pyr2,
                            const float* __restrict__ pyr3,
                            const float* __restrict__ ws_params,
                            float* __restrict__ out,
                            float* __restrict__ gridOut)
{
    const int n    = blockIdx.y;
    const int tile = blockIdx.x;                 // 4 across x 32 down
    const int tid  = threadIdx.x;
    const int w0 = (tile & 3) << 6;              // 64-px wide tile
    const int h0 = (tile >> 2) << 3;             // 8-px tall
    const int w  = w0 + ((tid & 31) << 1);       // even; this thread does w, w+1
    const int h  = h0 + (tid >> 5);

    const float* P = ws_params + n * 8;
    float m00 = P[0], m01 = P[1], m02 = P[2];
    float m10 = P[3], m11 = P[4], m12 = P[5];
    float lv  = P[6];

    const float STEP = 2.0f / (float)W_IMG;      // gx increment per +1 px
    float gx = ((float)w + 0.5f) * STEP - 1.0f;
    float gy = ((float)h + 0.5f) * (2.0f / (float)H_IMG) - 1.0f;
    float X0 = m00 * gx + m01 * gy + m02;
    float Y0 = m10 * gx + m11 * gy + m12;
    float X1 = X0 + m00 * STEP;
    float Y1 = Y0 + m10 * STEP;

    // grid (N,H,W,2): two px -> one v4f nt-store, perfectly coalesced
    v4f gq = {X0, Y0, X1, Y1};
    v4f* g4 = (v4f*)gridOut + (((size_t)(n * H_IMG + h) * W_IMG + w) >> 1);
    __builtin_nontemporal_store(gq, g4);

    int   l0   = (int)lv;          // lv in [0, 2.5]: trunc == floor
    float frac = lv - (float)l0;

    const int Wl0 = W_IMG >> l0,       Hl0 = H_IMG >> l0;
    const int Wl1 = W_IMG >> (l0 + 1), Hl1 = H_IMG >> (l0 + 1);
    const float* base0 = lvl_ptr(l0, img, pyr1, pyr2, pyr3) + (size_t)n * C_CH * Hl0 * Wl0;

    float a0[3], b0[3];
    sample_level_pair(base0, l0, X0, Y0, a0);
    sample_level_pair(base0, l0, X1, Y1, b0);

    float rA[3], rB[3];
    if (frac > 0.0f) {             // batch-uniform branch
        const float* base1 = lvl_ptr(l0 + 1, img, pyr1, pyr2, pyr3)
                           + (size_t)n * C_CH * Hl1 * Wl1;
        float a1[3], b1[3];
        sample_level_pair(base1, l0 + 1, X0, Y0, a1);
        sample_level_pair(base1, l0 + 1, X1, Y1, b1);
        float wA = 1.0f - frac;
#pragma unroll
        for (int c = 0; c < C_CH; c++) {
            rA[c] = wA * a0[c] + frac * a1[c];
            rB[c] = wA * b0[c] + frac * b1[c];
        }
    } else {
#pragma unroll
        for (int c = 0; c < C_CH; c++) { rA[c] = a0[c]; rB[c] = b0[c]; }
    }

    size_t base = ((size_t)n * C_CH * H_IMG + h) * W_IMG + w;
#pragma unroll
    for (int c = 0; c < C_CH; c++) {
        v2f o = {rA[c], rB[c]};
        __builtin_nontemporal_store(o, (v2f*)(out + base + (size_t)c * H_IMG * W_IMG));
    }
}

// ------------------------------------------------------------------
extern "C" void kernel_launch(void* const* d_in, const int* in_sizes, int n_in,
                              void* d_out, int out_size, void* d_ws, size_t ws_size,
                              hipStream_t stream)
{
    const float* img      = (const float*)d_in[0];
    const float* features = (const float*)d_in[1];
    const float* lin_w    = (const float*)d_in[2];
    const float* lin_b    = (const float*)d_in[3];

    float* out        = (float*)d_out;
    float* gridOut    = out + OUT_OFF_GRID;
    float* out_matrix = out + OUT_OFF_MATRIX;
    float* out_affine = out + OUT_OFF_AFFINE;

    float* ws        = (float*)d_ws;
    float* ws_params = ws;
    float* pyr1 = ws + 1024;                              // 64*3*128*128
    float* pyr2 = pyr1 + (size_t)N_B * C_CH * 128 * 128;  // 64*3*64*64
    float* pyr3 = pyr2 + (size_t)N_B * C_CH * 64 * 64;    // 64*3*32*32

    params_kernel<<<N_B, 256, 0, stream>>>(features, lin_w, lin_b,
                                           out_matrix, out_affine, ws_params);

    // level L sampled only when lv > L-1  ->  gate = L-1
    int t1 = N_B * C_CH * 128 * 32;
    down_kernel<256, 256><<<t1 / 256, 256, 0, stream>>>(img,  pyr1, ws_params, 0.0f);
    int t2 = N_B * C_CH * 64 * 16;
    down_kernel<128, 128><<<t2 / 256, 256, 0, stream>>>(pyr1, pyr2, ws_params, 1.0f);
    int t3 = N_B * C_CH * 32 * 8;
    down_kernel<64, 64><<<t3 / 256, 256, 0, stream>>>(pyr2, pyr3, ws_params, 2.0f);

    // 128 tiles (4x32) per batch; 2 px per thread
    warp_kernel<<<dim3(128, N_B), 256, 0, stream>>>(
        img, pyr1, pyr2, pyr3, ws_params, out, gridOut);
}

// Round 7
// 177.615 us; speedup vs baseline: 1.0228x; 1.0228x over previous
//
#include <hip/hip_runtime.h>
#include <math.h>

// Problem constants (N,C,H,W,D) = (64, 3, 256, 256, 512)
#define N_B 64
#define C_CH 3
#define H_IMG 256
#define W_IMG 256
#define D_FEAT 512

#define OUT_OFF_GRID   12582912
#define OUT_OFF_MATRIX 20971520
#define OUT_OFF_AFFINE 20971904

// native clang vectors (accepted by __builtin_nontemporal_store)
typedef float v2f __attribute__((ext_vector_type(2)));

// ------------------------------------------------------------------
// Kernel 1: per-batch linear head -> affine matrix + level
// ------------------------------------------------------------------
__global__ void params_kernel(const float* __restrict__ features,
                              const float* __restrict__ lin_w,
                              const float* __restrict__ lin_b,
                              float* __restrict__ out_matrix,
                              float* __restrict__ out_affine,
                              float* __restrict__ ws_params)
{
    const int n = blockIdx.x;
    const int t = threadIdx.x;
    const float* f = features + n * D_FEAT;
    float f0 = f[t];
    float f1 = f[t + 256];
    float a0 = f0 * lin_w[0 * D_FEAT + t] + f1 * lin_w[0 * D_FEAT + t + 256];
    float a1 = f0 * lin_w[1 * D_FEAT + t] + f1 * lin_w[1 * D_FEAT + t + 256];
    float a2 = f0 * lin_w[2 * D_FEAT + t] + f1 * lin_w[2 * D_FEAT + t + 256];
    float a3 = f0 * lin_w[3 * D_FEAT + t] + f1 * lin_w[3 * D_FEAT + t + 256];

    __shared__ float red[4][256];
    red[0][t] = a0; red[1][t] = a1; red[2][t] = a2; red[3][t] = a3;
    __syncthreads();
    for (int s = 128; s > 0; s >>= 1) {
        if (t < s) {
            red[0][t] += red[0][t + s];
            red[1][t] += red[1][t + s];
            red[2][t] += red[2][t + s];
            red[3][t] += red[3][t + s];
        }
        __syncthreads();
    }
    if (t == 0) {
        float p0 = red[0][0] + lin_b[0];
        float p1 = red[1][0] + lin_b[1];
        float p2 = red[2][0] + lin_b[2];
        float p3 = red[3][0] + lin_b[3];
        float rot   = tanhf(p0) * 3.14159265358979323846f;
        float scale = expf(p1);
        float c = cosf(rot), s = sinf(rot);
        float m00 = scale * c, m01 = -scale * s, m02 = p2;
        float m10 = scale * s, m11 =  scale * c, m12 = p3;
        out_matrix[n * 6 + 0] = m00;
        out_matrix[n * 6 + 1] = m01;
        out_matrix[n * 6 + 2] = m02;
        out_matrix[n * 6 + 3] = m10;
        out_matrix[n * 6 + 4] = m11;
        out_matrix[n * 6 + 5] = m12;
        out_affine[n * 4 + 0] = rot;
        out_affine[n * 4 + 1] = scale;
        out_affine[n * 4 + 2] = p2;
        out_affine[n * 4 + 3] = p3;
        // affine grid => Jacobian norm is exactly `scale` in both directions
        float lv = log2f(fmaxf(scale, 1.0f));
        lv = fminf(fmaxf(lv, 0.0f), 2.5f);
        ws_params[n * 8 + 0] = m00;
        ws_params[n * 8 + 1] = m01;
        ws_params[n * 8 + 2] = m02;
        ws_params[n * 8 + 3] = m10;
        ws_params[n * 8 + 4] = m11;
        ws_params[n * 8 + 5] = m12;
        ws_params[n * 8 + 6] = lv;
        ws_params[n * 8 + 7] = 0.0f;
    }
}

// ------------------------------------------------------------------
// Kernel 2: depthwise 4x4 binomial blur, reflect (1,2), stride 2.
// Early-exits whole image planes whose pyramid level is never sampled
// (block-uniform: blocks never straddle an (n,c) plane).
// ------------------------------------------------------------------
template<int Hs, int Ws>
__global__ void down_kernel(const float* __restrict__ src, float* __restrict__ dst,
                            const float* __restrict__ ws_params, float lvl_gate)
{
    constexpr int Hd = Hs / 2, Wd = Ws / 2;
    constexpr int QUADS = Wd / 4;

    const int idx = blockIdx.x * blockDim.x + threadIdx.x;
    const int nc  = idx / (QUADS * Hd);          // pow2 divisor
    const int n   = nc / C_CH;

    // this level is sampled only if lv > lvl_gate for batch n
    if (ws_params[n * 8 + 6] <= lvl_gate) return;

    const int t   = idx & (QUADS - 1);
    const int i   = (idx / QUADS) & (Hd - 1);

    const float* __restrict__ s = src + (size_t)nc * Hs * Ws;

    int r[4];
#pragma unroll
    for (int a = 0; a < 4; a++) {
        int q = 2 * i + a - 1;
        if (q < 0) q = -q;
        if (q >= Hs) q = 2 * Hs - 2 - q;
        r[a] = q;
    }
    const int c8 = 8 * t;
    const int li = (t > 0)         ? c8 - 1 : 1;       // reflect -1 -> 1
    const int ri = (t < QUADS - 1) ? c8 + 8 : Ws - 2;  // reflect Ws -> Ws-2

    const float k0 = 0.125f, k1 = 0.375f;
    const float kr[4] = {0.125f, 0.375f, 0.375f, 0.125f};

    float acc0 = 0.f, acc1 = 0.f, acc2 = 0.f, acc3 = 0.f;
#pragma unroll
    for (int a = 0; a < 4; a++) {
        const float* row = s + (size_t)r[a] * Ws;
        float4 A = *(const float4*)(row + c8);
        float4 B = *(const float4*)(row + c8 + 4);
        float L = row[li];
        float R = row[ri];
        float h0 = k0 * L   + k1 * A.x + k1 * A.y + k0 * A.z;
        float h1 = k0 * A.y + k1 * A.z + k1 * A.w + k0 * B.x;
        float h2 = k0 * A.w + k1 * B.x + k1 * B.y + k0 * B.z;
        float h3 = k0 * B.y + k1 * B.z + k1 * B.w + k0 * R;
        acc0 += kr[a] * h0;
        acc1 += kr[a] * h1;
        acc2 += kr[a] * h2;
        acc3 += kr[a] * h3;
    }
    float4* d4 = (float4*)(dst + (size_t)nc * Hd * Wd + (size_t)i * Wd + 4 * t);
    *d4 = make_float4(acc0, acc1, acc2, acc3);
}

// ------------------------------------------------------------------
// Kernel 3: affine grid + mipmap bilinear warp.
// 1 px/thread; 16x4 wave sub-tiles (compact footprint — measured best);
// x-tap pairs fetched as one (unaligned-ok) float2; nt-stores.
// ------------------------------------------------------------------
__device__ __forceinline__ const float* lvl_ptr(int l, const float* img,
                                                const float* p1, const float* p2,
                                                const float* p3)
{
    return (l == 0) ? img : ((l == 1) ? p1 : ((l == 2) ? p2 : p3));
}

// bilinear sample of 3 channels at level l using paired x-loads
__device__ __forceinline__ void sample_level_pair(const float* __restrict__ p, int n, int l,
                                                  float X, float Y, float out[3])
{
    const int Wl = W_IMG >> l;
    const int Hl = H_IMG >> l;
    float x = (X + 1.0f) * (0.5f * (float)Wl) - 0.5f;
    float y = (Y + 1.0f) * (0.5f * (float)Hl) - 0.5f;
    float x0f = floorf(x), y0f = floorf(y);
    float tx = x - x0f, ty = y - y0f;
    int x0 = (int)x0f, y0 = (int)y0f;
    int y0i = min(max(y0,     0), Hl - 1);
    int y1i = min(max(y0 + 1, 0), Hl - 1);
    int xp = min(max(x0, 0), Wl - 2);     // pair base col: [xp, xp+1] in range
    const bool selHi0 = (x0 >= Wl - 1);   // tap0 takes .y (right border clamp)
    const bool selLo1 = (x0 < 0);         // tap1 takes .x (left border clamp)
    float w00 = (1.0f - tx) * (1.0f - ty);
    float w01 = tx * (1.0f - ty);
    float w10 = (1.0f - tx) * ty;
    float w11 = tx * ty;
    const float* base = p + (size_t)n * C_CH * Hl * Wl;
#pragma unroll
    for (int c = 0; c < C_CH; c++) {
        const float* pc = base + (size_t)c * Hl * Wl;
        float2 a = *(const float2*)(pc + y0i * Wl + xp);
        float2 b = *(const float2*)(pc + y1i * Wl + xp);
        float t00 = selHi0 ? a.y : a.x;
        float t01 = selLo1 ? a.x : a.y;
        float t10 = selHi0 ? b.y : b.x;
        float t11 = selLo1 ? b.x : b.y;
        out[c] = w00 * t00 + w01 * t01 + w10 * t10 + w11 * t11;
    }
}

__global__ void warp_kernel(const float* __restrict__ img,
                            const float* __restrict__ pyr1,
                            const float* __restrict__ pyr2,
                            const float* __restrict__ pyr3,
                            const float* __restrict__ ws_params,
                            float* __restrict__ out,
                            float* __restrict__ gridOut)
{
    const int n = blockIdx.y;
    const int tile = blockIdx.x;
    const int tid = threadIdx.x;
    // block covers 32x8; each 64-lane wave covers a 16x4 sub-tile
    const int w0 = (tile & 7) << 5;
    const int h0 = (tile >> 3) << 3;
    const int w = w0 + (((tid >> 6) & 1) << 4) + (tid & 15);
    const int h = h0 + ((tid >> 7) << 2) + ((tid >> 4) & 3);

    const float* P = ws_params + n * 8;
    float m00 = P[0], m01 = P[1], m02 = P[2];
    float m10 = P[3], m11 = P[4], m12 = P[5];
    float lv  = P[6];

    float gx = ((float)w + 0.5f) * (2.0f / (float)W_IMG) - 1.0f;
    float gy = ((float)h + 0.5f) * (2.0f / (float)H_IMG) - 1.0f;
    float X = m00 * gx + m01 * gy + m02;
    float Y = m10 * gx + m11 * gy + m12;

    // grid output (N,H,W,2) — never re-read: one v2f nt-store
    v2f gp = {X, Y};
    __builtin_nontemporal_store(gp, (v2f*)gridOut + ((size_t)(n * H_IMG + h) * W_IMG + w));

    int   l0   = (int)lv;          // lv in [0, 2.5]: trunc == floor
    float frac = lv - (float)l0;

    float c0[3];
    sample_level_pair(lvl_ptr(l0, img, pyr1, pyr2, pyr3), n, l0, X, Y, c0);

    float r0, r1, r2;
    if (frac > 0.0f) {             // batch-uniform branch
        float c1[3];
        sample_level_pair(lvl_ptr(l0 + 1, img, pyr1, pyr2, pyr3), n, l0 + 1, X, Y, c1);
        float wA = 1.0f - frac;
        r0 = wA * c0[0] + frac * c1[0];
        r1 = wA * c0[1] + frac * c1[1];
        r2 = wA * c0[2] + frac * c1[2];
    } else {
        r0 = c0[0]; r1 = c0[1]; r2 = c0[2];
    }

    size_t base = ((size_t)n * C_CH * H_IMG + h) * W_IMG + w;
    __builtin_nontemporal_store(r0, out + base);
    __builtin_nontemporal_store(r1, out + base + (size_t)H_IMG * W_IMG);
    __builtin_nontemporal_store(r2, out + base + (size_t)2 * H_IMG * W_IMG);
}

// ------------------------------------------------------------------
extern "C" void kernel_launch(void* const* d_in, const int* in_sizes, int n_in,
                              void* d_out, int out_size, void* d_ws, size_t ws_size,
                              hipStream_t stream)
{
    const float* img      = (const float*)d_in[0];
    const float* features = (const float*)d_in[1];
    const float* lin_w    = (const float*)d_in[2];
    const float* lin_b    = (const float*)d_in[3];

    float* out        = (float*)d_out;
    float* gridOut    = out + OUT_OFF_GRID;
    float* out_matrix = out + OUT_OFF_MATRIX;
    float* out_affine = out + OUT_OFF_AFFINE;

    float* ws        = (float*)d_ws;
    float* ws_params = ws;
    float* pyr1 = ws + 1024;                              // 64*3*128*128
    float* pyr2 = pyr1 + (size_t)N_B * C_CH * 128 * 128;  // 64*3*64*64
    float* pyr3 = pyr2 + (size_t)N_B * C_CH * 64 * 64;    // 64*3*32*32

    params_kernel<<<N_B, 256, 0, stream>>>(features, lin_w, lin_b,
                                           out_matrix, out_affine, ws_params);

    // level L sampled only when lv > L-1  ->  gate = L-1
    int t1 = N_B * C_CH * 128 * 32;
    down_kernel<256, 256><<<t1 / 256, 256, 0, stream>>>(img,  pyr1, ws_params, 0.0f);
    int t2 = N_B * C_CH * 64 * 16;
    down_kernel<128, 128><<<t2 / 256, 256, 0, stream>>>(pyr1, pyr2, ws_params, 1.0f);
    int t3 = N_B * C_CH * 32 * 8;
    down_kernel<64, 64><<<t3 / 256, 256, 0, stream>>>(pyr2, pyr3, ws_params, 2.0f);

    warp_kernel<<<dim3(H_IMG * W_IMG / 256, N_B), 256, 0, stream>>>(
        img, pyr1, pyr2, pyr3, ws_params, out, gridOut);
}

// Round 8
// 171.924 us; speedup vs baseline: 1.0567x; 1.0331x over previous
//
#include <hip/hip_runtime.h>
#include <math.h>

// Problem constants (N,C,H,W,D) = (64, 3, 256, 256, 512)
#define N_B 64
#define C_CH 3
#define H_IMG 256
#define W_IMG 256
#define D_FEAT 512

#define OUT_OFF_GRID   12582912
#define OUT_OFF_MATRIX 20971520
#define OUT_OFF_AFFINE 20971904

// native clang vector (accepted by __builtin_nontemporal_store)
typedef float v2f __attribute__((ext_vector_type(2)));

// ------------------------------------------------------------------
// Kernel 1: per-batch linear head -> affine matrix + level
// ------------------------------------------------------------------
__global__ void params_kernel(const float* __restrict__ features,
                              const float* __restrict__ lin_w,
                              const float* __restrict__ lin_b,
                              float* __restrict__ out_matrix,
                              float* __restrict__ out_affine,
                              float* __restrict__ ws_params)
{
    const int n = blockIdx.x;
    const int t = threadIdx.x;
    const float* f = features + n * D_FEAT;
    float f0 = f[t];
    float f1 = f[t + 256];
    float a0 = f0 * lin_w[0 * D_FEAT + t] + f1 * lin_w[0 * D_FEAT + t + 256];
    float a1 = f0 * lin_w[1 * D_FEAT + t] + f1 * lin_w[1 * D_FEAT + t + 256];
    float a2 = f0 * lin_w[2 * D_FEAT + t] + f1 * lin_w[2 * D_FEAT + t + 256];
    float a3 = f0 * lin_w[3 * D_FEAT + t] + f1 * lin_w[3 * D_FEAT + t + 256];

    __shared__ float red[4][256];
    red[0][t] = a0; red[1][t] = a1; red[2][t] = a2; red[3][t] = a3;
    __syncthreads();
    for (int s = 128; s > 0; s >>= 1) {
        if (t < s) {
            red[0][t] += red[0][t + s];
            red[1][t] += red[1][t + s];
            red[2][t] += red[2][t + s];
            red[3][t] += red[3][t + s];
        }
        __syncthreads();
    }
    if (t == 0) {
        float p0 = red[0][0] + lin_b[0];
        float p1 = red[1][0] + lin_b[1];
        float p2 = red[2][0] + lin_b[2];
        float p3 = red[3][0] + lin_b[3];
        float rot   = tanhf(p0) * 3.14159265358979323846f;
        float scale = expf(p1);
        float c = cosf(rot), s = sinf(rot);
        float m00 = scale * c, m01 = -scale * s, m02 = p2;
        float m10 = scale * s, m11 =  scale * c, m12 = p3;
        out_matrix[n * 6 + 0] = m00;
        out_matrix[n * 6 + 1] = m01;
        out_matrix[n * 6 + 2] = m02;
        out_matrix[n * 6 + 3] = m10;
        out_matrix[n * 6 + 4] = m11;
        out_matrix[n * 6 + 5] = m12;
        out_affine[n * 4 + 0] = rot;
        out_affine[n * 4 + 1] = scale;
        out_affine[n * 4 + 2] = p2;
        out_affine[n * 4 + 3] = p3;
        // affine grid => Jacobian norm is exactly `scale` in both directions
        float lv = log2f(fmaxf(scale, 1.0f));
        lv = fminf(fmaxf(lv, 0.0f), 2.5f);
        ws_params[n * 8 + 0] = m00;
        ws_params[n * 8 + 1] = m01;
        ws_params[n * 8 + 2] = m02;
        ws_params[n * 8 + 3] = m10;
        ws_params[n * 8 + 4] = m11;
        ws_params[n * 8 + 5] = m12;
        ws_params[n * 8 + 6] = lv;
        ws_params[n * 8 + 7] = 0.0f;
    }
}

// ------------------------------------------------------------------
// Kernel 2: depthwise 4x4 binomial blur, reflect (1,2), stride 2.
// Early-exits whole image planes whose pyramid level is never sampled
// (block-uniform: blocks never straddle an (n,c) plane).
// ------------------------------------------------------------------
template<int Hs, int Ws>
__global__ void down_kernel(const float* __restrict__ src, float* __restrict__ dst,
                            const float* __restrict__ ws_params, float lvl_gate)
{
    constexpr int Hd = Hs / 2, Wd = Ws / 2;
    constexpr int QUADS = Wd / 4;

    const int idx = blockIdx.x * blockDim.x + threadIdx.x;
    const int nc  = idx / (QUADS * Hd);          // pow2 divisor
    const int n   = nc / C_CH;

    // this level is sampled only if lv > lvl_gate for batch n
    if (ws_params[n * 8 + 6] <= lvl_gate) return;

    const int t   = idx & (QUADS - 1);
    const int i   = (idx / QUADS) & (Hd - 1);

    const float* __restrict__ s = src + (size_t)nc * Hs * Ws;

    int r[4];
#pragma unroll
    for (int a = 0; a < 4; a++) {
        int q = 2 * i + a - 1;
        if (q < 0) q = -q;
        if (q >= Hs) q = 2 * Hs - 2 - q;
        r[a] = q;
    }
    const int c8 = 8 * t;
    const int li = (t > 0)         ? c8 - 1 : 1;       // reflect -1 -> 1
    const int ri = (t < QUADS - 1) ? c8 + 8 : Ws - 2;  // reflect Ws -> Ws-2

    const float k0 = 0.125f, k1 = 0.375f;
    const float kr[4] = {0.125f, 0.375f, 0.375f, 0.125f};

    float acc0 = 0.f, acc1 = 0.f, acc2 = 0.f, acc3 = 0.f;
#pragma unroll
    for (int a = 0; a < 4; a++) {
        const float* row = s + (size_t)r[a] * Ws;
        float4 A = *(const float4*)(row + c8);
        float4 B = *(const float4*)(row + c8 + 4);
        float L = row[li];
        float R = row[ri];
        float h0 = k0 * L   + k1 * A.x + k1 * A.y + k0 * A.z;
        float h1 = k0 * A.y + k1 * A.z + k1 * A.w + k0 * B.x;
        float h2 = k0 * A.w + k1 * B.x + k1 * B.y + k0 * B.z;
        float h3 = k0 * B.y + k1 * B.z + k1 * B.w + k0 * R;
        acc0 += kr[a] * h0;
        acc1 += kr[a] * h1;
        acc2 += kr[a] * h2;
        acc3 += kr[a] * h3;
    }
    float4* d4 = (float4*)(dst + (size_t)nc * Hd * Wd + (size_t)i * Wd + 4 * t);
    *d4 = make_float4(acc0, acc1, acc2, acc3);
}

// ------------------------------------------------------------------
// Kernel 3: affine grid + mipmap bilinear warp.
// 1 px/thread; 16x4 wave sub-tiles (compact footprint — measured best);
// x-tap pairs fetched as one (unaligned-ok) float2.
// grid store: nt (exact 128-B lines). out stores: regular (L2 combines
// the 64-B half-wave segments; nt here amplified WRITE_SIZE 80->97 MB).
// ------------------------------------------------------------------
__device__ __forceinline__ const float* lvl_ptr(int l, const float* img,
                                                const float* p1, const float* p2,
                                                const float* p3)
{
    return (l == 0) ? img : ((l == 1) ? p1 : ((l == 2) ? p2 : p3));
}

// bilinear sample of 3 channels at level l using paired x-loads
__device__ __forceinline__ void sample_level_pair(const float* __restrict__ p, int n, int l,
                                                  float X, float Y, float out[3])
{
    const int Wl = W_IMG >> l;
    const int Hl = H_IMG >> l;
    float x = (X + 1.0f) * (0.5f * (float)Wl) - 0.5f;
    float y = (Y + 1.0f) * (0.5f * (float)Hl) - 0.5f;
    float x0f = floorf(x), y0f = floorf(y);
    float tx = x - x0f, ty = y - y0f;
    int x0 = (int)x0f, y0 = (int)y0f;
    int y0i = min(max(y0,     0), Hl - 1);
    int y1i = min(max(y0 + 1, 0), Hl - 1);
    int xp = min(max(x0, 0), Wl - 2);     // pair base col: [xp, xp+1] in range
    const bool selHi0 = (x0 >= Wl - 1);   // tap0 takes .y (right border clamp)
    const bool selLo1 = (x0 < 0);         // tap1 takes .x (left border clamp)
    float w00 = (1.0f - tx) * (1.0f - ty);
    float w01 = tx * (1.0f - ty);
    float w10 = (1.0f - tx) * ty;
    float w11 = tx * ty;
    const float* base = p + (size_t)n * C_CH * Hl * Wl;
#pragma unroll
    for (int c = 0; c < C_CH; c++) {
        const float* pc = base + (size_t)c * Hl * Wl;
        float2 a = *(const float2*)(pc + y0i * Wl + xp);
        float2 b = *(const float2*)(pc + y1i * Wl + xp);
        float t00 = selHi0 ? a.y : a.x;
        float t01 = selLo1 ? a.x : a.y;
        float t10 = selHi0 ? b.y : b.x;
        float t11 = selLo1 ? b.x : b.y;
        out[c] = w00 * t00 + w01 * t01 + w10 * t10 + w11 * t11;
    }
}

__global__ void warp_kernel(const float* __restrict__ img,
                            const float* __restrict__ pyr1,
                            const float* __restrict__ pyr2,
                            const float* __restrict__ pyr3,
                            const float* __restrict__ ws_params,
                            float* __restrict__ out,
                            float* __restrict__ gridOut)
{
    const int n = blockIdx.y;
    const int tile = blockIdx.x;
    const int tid = threadIdx.x;
    // block covers 32x8; each 64-lane wave covers a 16x4 sub-tile
    const int w0 = (tile & 7) << 5;
    const int h0 = (tile >> 3) << 3;
    const int w = w0 + (((tid >> 6) & 1) << 4) + (tid & 15);
    const int h = h0 + ((tid >> 7) << 2) + ((tid >> 4) & 3);

    const float* P = ws_params + n * 8;
    float m00 = P[0], m01 = P[1], m02 = P[2];
    float m10 = P[3], m11 = P[4], m12 = P[5];
    float lv  = P[6];

    float gx = ((float)w + 0.5f) * (2.0f / (float)W_IMG) - 1.0f;
    float gy = ((float)h + 0.5f) * (2.0f / (float)H_IMG) - 1.0f;
    float X = m00 * gx + m01 * gy + m02;
    float Y = m10 * gx + m11 * gy + m12;

    // grid output (N,H,W,2) — never re-read: one v2f nt-store (full lines)
    v2f gp = {X, Y};
    __builtin_nontemporal_store(gp, (v2f*)gridOut + ((size_t)(n * H_IMG + h) * W_IMG + w));

    int   l0   = (int)lv;          // lv in [0, 2.5]: trunc == floor
    float frac = lv - (float)l0;

    float c0[3];
    sample_level_pair(lvl_ptr(l0, img, pyr1, pyr2, pyr3), n, l0, X, Y, c0);

    float r0, r1, r2;
    if (frac > 0.0f) {             // batch-uniform branch
        float c1[3];
        sample_level_pair(lvl_ptr(l0 + 1, img, pyr1, pyr2, pyr3), n, l0 + 1, X, Y, c1);
        float wA = 1.0f - frac;
        r0 = wA * c0[0] + frac * c1[0];
        r1 = wA * c0[1] + frac * c1[1];
        r2 = wA * c0[2] + frac * c1[2];
    } else {
        r0 = c0[0]; r1 = c0[1]; r2 = c0[2];
    }

    size_t base = ((size_t)n * C_CH * H_IMG + h) * W_IMG + w;
    out[base]                             = r0;
    out[base + (size_t)H_IMG * W_IMG]     = r1;
    out[base + (size_t)2 * H_IMG * W_IMG] = r2;
}

// ------------------------------------------------------------------
extern "C" void kernel_launch(void* const* d_in, const int* in_sizes, int n_in,
                              void* d_out, int out_size, void* d_ws, size_t ws_size,
                              hipStream_t stream)
{
    const float* img      = (const float*)d_in[0];
    const float* features = (const float*)d_in[1];
    const float* lin_w    = (const float*)d_in[2];
    const float* lin_b    = (const float*)d_in[3];

    float* out        = (float*)d_out;
    float* gridOut    = out + OUT_OFF_GRID;
    float* out_matrix = out + OUT_OFF_MATRIX;
    float* out_affine = out + OUT_OFF_AFFINE;

    float* ws        = (float*)d_ws;
    float* ws_params = ws;
    float* pyr1 = ws + 1024;                              // 64*3*128*128
    float* pyr2 = pyr1 + (size_t)N_B * C_CH * 128 * 128;  // 64*3*64*64
    float* pyr3 = pyr2 + (size_t)N_B * C_CH * 64 * 64;    // 64*3*32*32

    params_kernel<<<N_B, 256, 0, stream>>>(features, lin_w, lin_b,
                                           out_matrix, out_affine, ws_params);

    // level L sampled only when lv > L-1  ->  gate = L-1
    int t1 = N_B * C_CH * 128 * 32;
    down_kernel<256, 256><<<t1 / 256, 256, 0, stream>>>(img,  pyr1, ws_params, 0.0f);
    int t2 = N_B * C_CH * 64 * 16;
    down_kernel<128, 128><<<t2 / 256, 256, 0, stream>>>(pyr1, pyr2, ws_params, 1.0f);
    int t3 = N_B * C_CH * 32 * 8;
    down_kernel<64, 64><<<t3 / 256, 256, 0, stream>>>(pyr2, pyr3, ws_params, 2.0f);

    warp_kernel<<<dim3(H_IMG * W_IMG / 256, N_B), 256, 0, stream>>>(
        img, pyr1, pyr2, pyr3, ws_params, out, gridOut);
}

// Round 9
// 170.881 us; speedup vs baseline: 1.0631x; 1.0061x over previous
//
#include <hip/hip_runtime.h>
#include <math.h>

// Problem constants (N,C,H,W,D) = (64, 3, 256, 256, 512)
#define N_B 64
#define C_CH 3
#define H_IMG 256
#define W_IMG 256
#define D_FEAT 512

#define OUT_OFF_GRID   12582912
#define OUT_OFF_MATRIX 20971520
#define OUT_OFF_AFFINE 20971904

// native clang vector (accepted by __builtin_nontemporal_store)
typedef float v2f __attribute__((ext_vector_type(2)));

// ------------------------------------------------------------------
// Kernel 1: per-batch linear head -> affine matrix + level
// ------------------------------------------------------------------
__global__ void params_kernel(const float* __restrict__ features,
                              const float* __restrict__ lin_w,
                              const float* __restrict__ lin_b,
                              float* __restrict__ out_matrix,
                              float* __restrict__ out_affine,
                              float* __restrict__ ws_params)
{
    const int n = blockIdx.x;
    const int t = threadIdx.x;
    const float* f = features + n * D_FEAT;
    float f0 = f[t];
    float f1 = f[t + 256];
    float a0 = f0 * lin_w[0 * D_FEAT + t] + f1 * lin_w[0 * D_FEAT + t + 256];
    float a1 = f0 * lin_w[1 * D_FEAT + t] + f1 * lin_w[1 * D_FEAT + t + 256];
    float a2 = f0 * lin_w[2 * D_FEAT + t] + f1 * lin_w[2 * D_FEAT + t + 256];
    float a3 = f0 * lin_w[3 * D_FEAT + t] + f1 * lin_w[3 * D_FEAT + t + 256];

    __shared__ float red[4][256];
    red[0][t] = a0; red[1][t] = a1; red[2][t] = a2; red[3][t] = a3;
    __syncthreads();
    for (int s = 128; s > 0; s >>= 1) {
        if (t < s) {
            red[0][t] += red[0][t + s];
            red[1][t] += red[1][t + s];
            red[2][t] += red[2][t + s];
            red[3][t] += red[3][t + s];
        }
        __syncthreads();
    }
    if (t == 0) {
        float p0 = red[0][0] + lin_b[0];
        float p1 = red[1][0] + lin_b[1];
        float p2 = red[2][0] + lin_b[2];
        float p3 = red[3][0] + lin_b[3];
        float rot   = tanhf(p0) * 3.14159265358979323846f;
        float scale = expf(p1);
        float c = cosf(rot), s = sinf(rot);
        float m00 = scale * c, m01 = -scale * s, m02 = p2;
        float m10 = scale * s, m11 =  scale * c, m12 = p3;
        out_matrix[n * 6 + 0] = m00;
        out_matrix[n * 6 + 1] = m01;
        out_matrix[n * 6 + 2] = m02;
        out_matrix[n * 6 + 3] = m10;
        out_matrix[n * 6 + 4] = m11;
        out_matrix[n * 6 + 5] = m12;
        out_affine[n * 4 + 0] = rot;
        out_affine[n * 4 + 1] = scale;
        out_affine[n * 4 + 2] = p2;
        out_affine[n * 4 + 3] = p3;
        // affine grid => Jacobian norm is exactly `scale` in both directions
        float lv = log2f(fmaxf(scale, 1.0f));
        lv = fminf(fmaxf(lv, 0.0f), 2.5f);
        ws_params[n * 8 + 0] = m00;
        ws_params[n * 8 + 1] = m01;
        ws_params[n * 8 + 2] = m02;
        ws_params[n * 8 + 3] = m10;
        ws_params[n * 8 + 4] = m11;
        ws_params[n * 8 + 5] = m12;
        ws_params[n * 8 + 6] = lv;
        ws_params[n * 8 + 7] = 0.0f;
    }
}

// ------------------------------------------------------------------
// Kernel 2: depthwise 4x4 binomial blur, reflect (1,2), stride 2.
// Early-exits whole image planes whose pyramid level is never sampled
// (block-uniform: blocks never straddle an (n,c) plane).
// ------------------------------------------------------------------
template<int Hs, int Ws>
__global__ void down_kernel(const float* __restrict__ src, float* __restrict__ dst,
                            const float* __restrict__ ws_params, float lvl_gate)
{
    constexpr int Hd = Hs / 2, Wd = Ws / 2;
    constexpr int QUADS = Wd / 4;

    const int idx = blockIdx.x * blockDim.x + threadIdx.x;
    const int nc  = idx / (QUADS * Hd);          // pow2 divisor
    const int n   = nc / C_CH;

    // this level is sampled only if lv > lvl_gate for batch n
    if (ws_params[n * 8 + 6] <= lvl_gate) return;

    const int t   = idx & (QUADS - 1);
    const int i   = (idx / QUADS) & (Hd - 1);

    const float* __restrict__ s = src + (size_t)nc * Hs * Ws;

    int r[4];
#pragma unroll
    for (int a = 0; a < 4; a++) {
        int q = 2 * i + a - 1;
        if (q < 0) q = -q;
        if (q >= Hs) q = 2 * Hs - 2 - q;
        r[a] = q;
    }
    const int c8 = 8 * t;
    const int li = (t > 0)         ? c8 - 1 : 1;       // reflect -1 -> 1
    const int ri = (t < QUADS - 1) ? c8 + 8 : Ws - 2;  // reflect Ws -> Ws-2

    const float k0 = 0.125f, k1 = 0.375f;
    const float kr[4] = {0.125f, 0.375f, 0.375f, 0.125f};

    float acc0 = 0.f, acc1 = 0.f, acc2 = 0.f, acc3 = 0.f;
#pragma unroll
    for (int a = 0; a < 4; a++) {
        const float* row = s + (size_t)r[a] * Ws;
        float4 A = *(const float4*)(row + c8);
        float4 B = *(const float4*)(row + c8 + 4);
        float L = row[li];
        float R = row[ri];
        float h0 = k0 * L   + k1 * A.x + k1 * A.y + k0 * A.z;
        float h1 = k0 * A.y + k1 * A.z + k1 * A.w + k0 * B.x;
        float h2 = k0 * A.w + k1 * B.x + k1 * B.y + k0 * B.z;
        float h3 = k0 * B.y + k1 * B.z + k1 * B.w + k0 * R;
        acc0 += kr[a] * h0;
        acc1 += kr[a] * h1;
        acc2 += kr[a] * h2;
        acc3 += kr[a] * h3;
    }
    float4* d4 = (float4*)(dst + (size_t)nc * Hd * Wd + (size_t)i * Wd + 4 * t);
    *d4 = make_float4(acc0, acc1, acc2, acc3);
}

// ------------------------------------------------------------------
// Kernel 3: affine grid + mipmap bilinear warp.
// 1 px/thread; 16x4 wave sub-tiles. All tap loads for both levels are
// issued before any arithmetic (load-batching): needs VGPR headroom,
// hence __launch_bounds__(256,4) (<=128 VGPR, 16 waves/CU).
// ------------------------------------------------------------------
__device__ __forceinline__ const float* lvl_ptr(int l, const float* img,
                                                const float* p1, const float* p2,
                                                const float* p3)
{
    return (l == 0) ? img : ((l == 1) ? p1 : ((l == 2) ? p2 : p3));
}

struct TapSetup {
    const float* row0;   // + c*plane gives channel row ptrs
    const float* row1;
    float w00, w01, w10, w11;
    bool selHi0, selLo1;
    size_t planeStride;
};

__device__ __forceinline__ TapSetup make_taps(const float* __restrict__ base, int l,
                                              float X, float Y)
{
    const int Wl = W_IMG >> l;
    const int Hl = H_IMG >> l;
    float x = (X + 1.0f) * (0.5f * (float)Wl) - 0.5f;
    float y = (Y + 1.0f) * (0.5f * (float)Hl) - 0.5f;
    float x0f = floorf(x), y0f = floorf(y);
    float tx = x - x0f, ty = y - y0f;
    int x0 = (int)x0f, y0 = (int)y0f;
    int y0i = min(max(y0,     0), Hl - 1);
    int y1i = min(max(y0 + 1, 0), Hl - 1);
    int xp = min(max(x0, 0), Wl - 2);
    TapSetup ts;
    ts.row0 = base + (size_t)y0i * Wl + xp;
    ts.row1 = base + (size_t)y1i * Wl + xp;
    ts.selHi0 = (x0 >= Wl - 1);
    ts.selLo1 = (x0 < 0);
    ts.w00 = (1.0f - tx) * (1.0f - ty);
    ts.w01 = tx * (1.0f - ty);
    ts.w10 = (1.0f - tx) * ty;
    ts.w11 = tx * ty;
    ts.planeStride = (size_t)Hl * Wl;
    return ts;
}

__device__ __forceinline__ float tap_eval(const TapSetup& ts, float2 a, float2 b)
{
    float t00 = ts.selHi0 ? a.y : a.x;
    float t01 = ts.selLo1 ? a.x : a.y;
    float t10 = ts.selHi0 ? b.y : b.x;
    float t11 = ts.selLo1 ? b.x : b.y;
    return ts.w00 * t00 + ts.w01 * t01 + ts.w10 * t10 + ts.w11 * t11;
}

__global__ __launch_bounds__(256, 4)
void warp_kernel(const float* __restrict__ img,
                 const float* __restrict__ pyr1,
                 const float* __restrict__ pyr2,
                 const float* __restrict__ pyr3,
                 const float* __restrict__ ws_params,
                 float* __restrict__ out,
                 float* __restrict__ gridOut)
{
    const int n = blockIdx.y;
    const int tile = blockIdx.x;
    const int tid = threadIdx.x;
    // block covers 32x8; each 64-lane wave covers a 16x4 sub-tile
    const int w0 = (tile & 7) << 5;
    const int h0 = (tile >> 3) << 3;
    const int w = w0 + (((tid >> 6) & 1) << 4) + (tid & 15);
    const int h = h0 + ((tid >> 7) << 2) + ((tid >> 4) & 3);

    const float* P = ws_params + n * 8;
    float m00 = P[0], m01 = P[1], m02 = P[2];
    float m10 = P[3], m11 = P[4], m12 = P[5];
    float lv  = P[6];

    float gx = ((float)w + 0.5f) * (2.0f / (float)W_IMG) - 1.0f;
    float gy = ((float)h + 0.5f) * (2.0f / (float)H_IMG) - 1.0f;
    float X = m00 * gx + m01 * gy + m02;
    float Y = m10 * gx + m11 * gy + m12;

    // grid output (N,H,W,2) — never re-read: one v2f nt-store (full lines)
    v2f gp = {X, Y};
    __builtin_nontemporal_store(gp, (v2f*)gridOut + ((size_t)(n * H_IMG + h) * W_IMG + w));

    int   l0   = (int)lv;          // lv in [0, 2.5]: trunc == floor
    float frac = lv - (float)l0;
    const bool hasL1 = (frac > 0.0f);   // batch-uniform

    const int Hl0 = H_IMG >> l0, Wl0 = W_IMG >> l0;
    const float* base0 = lvl_ptr(l0, img, pyr1, pyr2, pyr3)
                       + (size_t)n * C_CH * Hl0 * Wl0;
    TapSetup t0 = make_taps(base0, l0, X, Y);

    // issue ALL level-l0 loads (6 float2) before any arithmetic
    float2 A0[C_CH], B0[C_CH];
#pragma unroll
    for (int c = 0; c < C_CH; c++) {
        A0[c] = *(const float2*)(t0.row0 + c * t0.planeStride);
        B0[c] = *(const float2*)(t0.row1 + c * t0.planeStride);
    }

    size_t obase = ((size_t)n * C_CH * H_IMG + h) * W_IMG + w;

    if (hasL1) {
        const int Hl1 = H_IMG >> (l0 + 1), Wl1 = W_IMG >> (l0 + 1);
        const float* base1 = lvl_ptr(l0 + 1, img, pyr1, pyr2, pyr3)
                           + (size_t)n * C_CH * Hl1 * Wl1;
        TapSetup t1 = make_taps(base1, l0 + 1, X, Y);

        // issue level-l1 loads while l0 loads are still in flight
        float2 A1[C_CH], B1[C_CH];
#pragma unroll
        for (int c = 0; c < C_CH; c++) {
            A1[c] = *(const float2*)(t1.row0 + c * t1.planeStride);
            B1[c] = *(const float2*)(t1.row1 + c * t1.planeStride);
        }

        float wA = 1.0f - frac;
#pragma unroll
        for (int c = 0; c < C_CH; c++) {
            float v0 = tap_eval(t0, A0[c], B0[c]);
            float v1 = tap_eval(t1, A1[c], B1[c]);
            out[obase + (size_t)c * H_IMG * W_IMG] = wA * v0 + frac * v1;
        }
    } else {
#pragma unroll
        for (int c = 0; c < C_CH; c++) {
            out[obase + (size_t)c * H_IMG * W_IMG] = tap_eval(t0, A0[c], B0[c]);
        }
    }
}

// ------------------------------------------------------------------
extern "C" void kernel_launch(void* const* d_in, const int* in_sizes, int n_in,
                              void* d_out, int out_size, void* d_ws, size_t ws_size,
                              hipStream_t stream)
{
    const float* img      = (const float*)d_in[0];
    const float* features = (const float*)d_in[1];
    const float* lin_w    = (const float*)d_in[2];
    const float* lin_b    = (const float*)d_in[3];

    float* out        = (float*)d_out;
    float* gridOut    = out + OUT_OFF_GRID;
    float* out_matrix = out + OUT_OFF_MATRIX;
    float* out_affine = out + OUT_OFF_AFFINE;

    float* ws        = (float*)d_ws;
    float* ws_params = ws;
    float* pyr1 = ws + 1024;                              // 64*3*128*128
    float* pyr2 = pyr1 + (size_t)N_B * C_CH * 128 * 128;  // 64*3*64*64
    float* pyr3 = pyr2 + (size_t)N_B * C_CH * 64 * 64;    // 64*3*32*32

    params_kernel<<<N_B, 256, 0, stream>>>(features, lin_w, lin_b,
                                           out_matrix, out_affine, ws_params);

    // level L sampled only when lv > L-1  ->  gate = L-1
    int t1 = N_B * C_CH * 128 * 32;
    down_kernel<256, 256><<<t1 / 256, 256, 0, stream>>>(img,  pyr1, ws_params, 0.0f);
    int t2 = N_B * C_CH * 64 * 16;
    down_kernel<128, 128><<<t2 / 256, 256, 0, stream>>>(pyr1, pyr2, ws_params, 1.0f);
    int t3 = N_B * C_CH * 32 * 8;
    down_kernel<64, 64><<<t3 / 256, 256, 0, stream>>>(pyr2, pyr3, ws_params, 2.0f);

    warp_kernel<<<dim3(H_IMG * W_IMG / 256, N_B), 256, 0, stream>>>(
        img, pyr1, pyr2, pyr3, ws_params, out, gridOut);
}